// Round 8
// baseline (658.658 us; speedup 1.0000x reference)
//
#include <hip/hip_runtime.h>
#include <math.h>

#define BATCH 2048
#define NN 64
#define FEAT 40
#define M 10
#define NWAVE 4
#define BLOCK 256
#define KS 65      // Kp row stride: (k*65+lane)%32 = (k+lane)%32 -> 2 lanes/bank = free

__device__ __forceinline__ float rl(float v, int l) {   // readlane, uniform l
    return __int_as_float(__builtin_amdgcn_readlane(__float_as_int(v), l));
}
__device__ __forceinline__ float wsum(float v) {
#pragma unroll
    for (int o = 32; o >= 1; o >>= 1) v += __shfl_xor(v, o, 64);
    return v;
}

// 4-wave block per batch element, ALL data in LDS (zero register arrays: the
// consistent 2x VALU inflation in R6/R7 was the allocator AGPR-homing
// xcol[40] and paying v_accvgpr copies on every access).
// Distances in Gram form (1 fma per (elem,f)); identical fma chains make the
// diagonal/duplicate distance cancel EXACTLY; d2<0.05 clamp is insurance
// (legit d2 in 40-D N(0,1) data concentrates near 80; only duplicates are
// below). LDL^T upper-triangle Schur, scaled-L^T stored in place, unmasked
// forward solves. Models sharing (ls,eps) share one factorization.
__global__ __launch_bounds__(BLOCK)
void muygps_kernel(
    const float* __restrict__ x,      // (20000, 40)
    const float* __restrict__ ls,     // (10,)
    const float* __restrict__ epsv,   // (10,)
    const int*   __restrict__ bidx,   // (2048,)
    const int*   __restrict__ nidx,   // (2048, 64)
    const float* __restrict__ tgt,    // (2048, 64, 10)
    float* __restrict__ out)          // pred(2048,10) | var(2048,10) | sigma(10)
{
    __shared__ float Kp[NN * KS];     // kernel matrix -> scaled L^T (16.6 KB)
    __shared__ float xnT[FEAT * NN];  // transposed neighbor features (10.2 KB)
    __shared__ float xb[FEAT];
    __shared__ float nrm[NN];         // |x_n|^2
    __shared__ float rv[NN];          // 1/D[k]
    __shared__ float zkc[NN];         // solved Kcross vector

    const int b    = blockIdx.x;
    const int tid  = threadIdx.x;
    const int w    = tid >> 6;        // wave 0..3
    const int lane = tid & 63;

    // ---- stage xnT (transposed: bank-conflict-free stride 64) and xb ----
    {
        const float* xr = x + (long)nidx[b * NN + lane] * FEAT;
        for (int q = w; q < FEAT / 4; q += NWAVE) {
            const float4 v = *(const float4*)(xr + 4 * q);
            xnT[(4 * q + 0) * NN + lane] = v.x;
            xnT[(4 * q + 1) * NN + lane] = v.y;
            xnT[(4 * q + 2) * NN + lane] = v.z;
            xnT[(4 * q + 3) * NN + lane] = v.w;
        }
        if (tid < FEAT / 4)
            *(float4*)(&xb[tid * 4]) = *(const float4*)(x + (long)bidx[b] * FEAT + tid * 4);
    }
    __syncthreads();

    // ---- neighbor norms (wave 0); fma chain IDENTICAL to the Gram loop so
    //      duplicate rows cancel exactly in d2 = ni + nj - 2g ----
    if (w == 0) {
        float a = 0.f;
        for (int f = 0; f < FEAT; ++f) {
            const float v = xnT[f * NN + lane];
            a = fmaf(v, v, a);
        }
        nrm[lane] = a;
    }
    __syncthreads();

    unsigned done = 0;
    const unsigned all = (1u << M) - 1u;
    while (true) {
        const int   lead = __ffs(~done) - 1;          // block-uniform
        const float lls  = ls[lead];
        const float lep  = epsv[lead];
        const float il   = -1.0f / lls;
        const float nl   = nrm[lane];

        // ---- Phase A: Kp rows via Gram form; wave w owns rows 16w..16w+15 ----
        for (int it = 0; it < 16; ++it) {
            const int i = (w << 4) + it;
            float g = 0.f;
            for (int f = 0; f < FEAT; ++f)
                g = fmaf(xnT[f * NN + i], xnT[f * NN + lane], g);  // bcast + read
            float d2 = nrm[i] + nl - 2.f * g;
            d2 = (d2 < 0.05f) ? 0.f : d2;             // duplicates -> exact 0
            float v = __expf(sqrtf(d2) * il);
            if (lane == i) v += lep;
            Kp[i * KS + lane] = v;
        }
        // crosswise kernel (wave 0, kept in a register)
        float kc = 0.f;
        if (w == 0) {
            float g = 0.f, nb = 0.f;
            for (int f = 0; f < FEAT; ++f) {
                const float bf = xb[f];
                g  = fmaf(bf, xnT[f * NN + lane], g);
                nb = fmaf(bf, bf, nb);
            }
            float d2 = nb + nl - 2.f * g;
            d2 = (d2 < 0.05f) ? 0.f : d2;
            kc = __expf(sqrtf(d2) * il);
        }
        __syncthreads();

        // ---- Phase B: LDL^T, upper-triangle Schur, 1 barrier per k ----
        for (int k = 0; k < NN; ++k) {
            const float dk = Kp[k * KS + k];           // broadcast
            const float rk = __builtin_amdgcn_rcpf(dk);
            if (tid == 0) rv[k] = rk;
            const float colv = Kp[k * KS + lane];      // frozen row k
            const float rkn  = -rk;
            for (int i = k + 1 + w; i < NN; i += NWAVE) {
                const float fik = Kp[k * KS + i] * rkn;        // -L[i][k]
                if (lane >= i)                                  // upper only
                    Kp[i * KS + lane] = fmaf(fik, colv, Kp[i * KS + lane]);
            }
            __syncthreads();
        }

        // ---- scale pass: row k -> L^T row (L[j][k] for j>k), zeros elsewhere ----
        for (int r = w; r < NN; r += NWAVE) {
            const float rr  = rv[r];
            const float val = Kp[r * KS + lane];
            Kp[r * KS + lane] = (lane > r) ? val * rr : 0.f;
        }
        __syncthreads();

        // ---- Phase C: 3 forward solves per wave (unit-L, unmasked: zeros do it) ----
        const int r0 = w, r1 = w + 4, r2 = w + 8;      // slot 0 = Kc, s>=1 -> model s-1
        auto act = [&](int s) -> bool {
            if (s == 0) return true;
            if (s > M) return false;
            const int mm = s - 1;
            return !(done & (1u << mm)) && ls[mm] == lls && epsv[mm] == lep;
        };
        const bool a0 = act(r0), a1 = act(r1), a2 = act(r2);
        const long yb = ((long)b * NN + lane) * M;
        float z0 = a0 ? (w == 0 ? kc : tgt[yb + r0 - 1]) : 0.f;
        float z1 = a1 ? tgt[yb + r1 - 1] : 0.f;
        float z2 = a2 ? tgt[yb + r2 - 1] : 0.f;
        for (int k = 0; k < NN - 1; ++k) {
            const float l = Kp[k * KS + lane];         // L[lane][k], 0 for lane<=k
            const float t0 = rl(z0, k), t1 = rl(z1, k), t2 = rl(z2, k);
            z0 = fmaf(-l, t0, z0);
            z1 = fmaf(-l, t1, z1);
            z2 = fmaf(-l, t2, z2);
        }
        if (w == 0) zkc[lane] = z0;
        __syncthreads();

        // ---- quadratic forms with D^-1; each wave emits its own models ----
        {
            const float rvl  = rv[lane];
            const float zc   = zkc[lane];
            const float quad = wsum(zc * zc * rvl);
            const float inv_bn = 1.0f / (float)(BATCH * NN);
            if (r0 >= 1 && a0) {
                const int mm = r0 - 1;
                const float pm = wsum(zc * z0 * rvl);
                const float sm = wsum(z0 * z0 * rvl);
                if (lane == 0) {
                    out[b * M + mm] = pm;
                    out[BATCH * M + b * M + mm] = 1.0f - quad;
                    atomicAdd(&out[2 * BATCH * M + mm], sm * inv_bn);
                }
            }
            if (a1) {
                const int mm = r1 - 1;
                const float pm = wsum(zc * z1 * rvl);
                const float sm = wsum(z1 * z1 * rvl);
                if (lane == 0) {
                    out[b * M + mm] = pm;
                    out[BATCH * M + b * M + mm] = 1.0f - quad;
                    atomicAdd(&out[2 * BATCH * M + mm], sm * inv_bn);
                }
            }
            if (r2 <= M && a2) {
                const int mm = r2 - 1;
                const float pm = wsum(zc * z2 * rvl);
                const float sm = wsum(z2 * z2 * rvl);
                if (lane == 0) {
                    out[b * M + mm] = pm;
                    out[BATCH * M + b * M + mm] = 1.0f - quad;
                    atomicAdd(&out[2 * BATCH * M + mm], sm * inv_bn);
                }
            }
        }

        // uniform done-update; loop again only for extra (ls,eps) groups
#pragma unroll
        for (int mm = 0; mm < M; ++mm)
            if (ls[mm] == lls && epsv[mm] == lep) done |= 1u << mm;
        if (done == all) break;
        __syncthreads();   // protect Kp/rv/zkc reuse across group iterations
    }
}

extern "C" void kernel_launch(void* const* d_in, const int* in_sizes, int n_in,
                              void* d_out, int out_size, void* d_ws, size_t ws_size,
                              hipStream_t stream) {
    const float* x   = (const float*)d_in[0];
    const float* lsp = (const float*)d_in[1];
    const float* ep  = (const float*)d_in[2];
    const int*   bi  = (const int*)d_in[3];
    const int*   ni  = (const int*)d_in[4];
    const float* tg  = (const float*)d_in[5];
    float* out = (float*)d_out;

    // sigma_sq region accumulated via atomics; d_out is poisoned each launch
    hipMemsetAsync(out + 2 * BATCH * M, 0, M * sizeof(float), stream);
    muygps_kernel<<<BATCH, BLOCK, 0, stream>>>(x, lsp, ep, bi, ni, tg, out);
}

// Round 9
// 410.316 us; speedup vs baseline: 1.6052x; 1.6052x over previous
//
#include <hip/hip_runtime.h>
#include <math.h>

#define BATCH 2048
#define NN 64
#define FEAT 40
#define M 10
// A holds the 64x64 matrix row-major (row i at word i*64). Offset-addressed
// rank-2 updates write up to word 63*64+60+63 and the scaled-row store up to
// 63*64+62+63 = 4157; spill lands only in already-dead (col<k) words. Pad.
#define ASZ (NN * NN + 130)

__device__ __forceinline__ float rl(float v, int l) {   // readlane, runtime idx ok
    return __int_as_float(__builtin_amdgcn_readlane(__float_as_int(v), l));
}
__device__ __forceinline__ float wsum(float v) {
#pragma unroll
    for (int o = 32; o >= 1; o >>= 1) v += __shfl_xor(v, o, 64);
    return v;
}

// One wave per batch element. Rolled loops (~2KB code: no I-cache streaming),
// matrix in LDS (no big register arrays: no AGPR copy tax), single wave (no
// barriers). Gram inner loop: row i in SGPRs (readfirstlane'd uniform addr ->
// s_load), lane's row in 40 static VGPRs -> 1 v_fma per feature, zero LDS.
// LDL^T keeps rows symmetric (full-row updates) so column k == row k: pivot
// data via 1 conflict-free row read + readlanes. Rank-2 steps halve LDS
// traffic. Models sharing (ls,eps) share one factorization (group loop runs
// once for the real inputs). Duplicate neighbors: identical fma chains give
// exact d2=0 (plus snap<0.05; legit d2 in 40-D N(0,1) data is ~80).
__global__ __launch_bounds__(64)
void muygps_kernel(
    const float* __restrict__ x,      // (20000, 40)
    const float* __restrict__ ls,     // (10,)
    const float* __restrict__ epsv,   // (10,)
    const int*   __restrict__ bidx,   // (2048,)
    const int*   __restrict__ nidx,   // (2048, 64)
    const float* __restrict__ tgt,    // (2048, 64, 10)
    float* __restrict__ out)          // pred(2048,10) | var(2048,10) | sigma(10)
{
    __shared__ float A[ASZ];
    __shared__ float rvb[NN];         // 1/D[k]

    const int b    = blockIdx.x;
    const int lane = threadIdx.x;     // one wave

    // ---- lane's neighbor row -> 40 statically-indexed VGPRs ----
    const float* xr0 = x + (size_t)nidx[b * NN + lane] * FEAT;
    float xc[FEAT];
#pragma unroll
    for (int q = 0; q < FEAT / 4; ++q) {
        const float4 v = *(const float4*)(xr0 + 4 * q);
        xc[4*q] = v.x; xc[4*q+1] = v.y; xc[4*q+2] = v.z; xc[4*q+3] = v.w;
    }
    float nl = 0.f;
#pragma unroll
    for (int f = 0; f < FEAT; ++f) nl = fmaf(xc[f], xc[f], nl);

    // ---- crosswise distance (batch point in scalar regs) ----
    const int bi = __builtin_amdgcn_readfirstlane(bidx[b]);
    const float* xbp = x + (size_t)bi * FEAT;
    float gc = 0.f, nb = 0.f;
#pragma unroll
    for (int f = 0; f < FEAT; ++f) {
        const float bf = xbp[f];      // uniform -> SGPR
        gc = fmaf(bf, xc[f], gc);
        nb = fmaf(bf, bf, nb);
    }
    float cd2 = (nb + nl) - 2.f * gc; // exact 0 if batch point == neighbor
    cd2 = (cd2 < 0.05f) ? 0.f : cd2;
    const float cdv = sqrtf(cd2);

    unsigned done = 0;
    const unsigned all = (1u << M) - 1u;
    while (true) {
        const int   lead = __ffs(~done) - 1;        // wave-uniform
        const float lls  = ls[lead];
        const float lep  = epsv[lead];
        const float il   = -1.0f / lls;

        // ---- Gram + kernel transform, rolled over rows ----
        for (int i = 0; i < NN; ++i) {
            const int ri = __builtin_amdgcn_readfirstlane(nidx[b * NN + i]);
            const float* xr = x + (size_t)ri * FEAT;   // uniform -> s_loads
            float g = 0.f;
#pragma unroll
            for (int f = 0; f < FEAT; ++f) g = fmaf(xr[f], xc[f], g);
            const float ni = rl(g, i);                 // diag of Gram = |x_i|^2
            float d2 = (ni + nl) - 2.f * g;            // dup rows -> exact 0
            d2 = (d2 < 0.05f) ? 0.f : d2;
            float v = __expf(sqrtf(d2) * il);
            if (lane == i) v += lep;
            A[i * NN + lane] = v;
        }
        const float kcv = __expf(cdv * il);

        // ---- rank-2 LDL^T; rows stay symmetric Schur rows ----
        for (int p = 0; p < NN / 2; ++p) {
            const int k  = 2 * p;
            const int kk = k * NN + k;                 // offset addressing
            const float colv0 = A[kk + lane];          // A[k][k+lane]
            const float d0  = rl(colv0, 0);
            const float r0  = __builtin_amdgcn_rcpf(d0);
            const float cv0 = colv0 * (-r0);
            const float l10 = rl(colv0, 1);            // A[k][k+1]
            float colv1 = A[kk + NN + lane];           // A[k+1][k+lane] raw
            colv1 = fmaf(cv0, l10, colv1);             // rank-1 fix row k+1
            const float d1  = rl(colv1, 1);
            const float r1  = __builtin_amdgcn_rcpf(d1);
            const float cv1 = colv1 * (-r1);
            // store scaled L columns in place (word k*64+j = L[j][k], j>k)
            A[kk + lane]      = (lane >= 1) ? colv0 * r0 : 0.f;
            A[kk + NN + lane] = (lane >= 2) ? colv1 * r1 : 0.f;
            rvb[k]     = r0;                            // same-addr bcast write
            rvb[k + 1] = r1;
#pragma unroll 4
            for (int i = k + 2; i < NN; ++i) {
                const float l0 = rl(colv0, i - k);     // A[i][k] (symmetry)
                const float l1 = rl(colv1, i - k);     // A[i][k+1] updated
                float t = A[i * NN + k + lane];        // A[i][k+lane]
                t = fmaf(cv0, l0, t);
                t = fmaf(cv1, l1, t);
                A[i * NN + k + lane] = t;              // spill -> dead words
            }
        }

        // ---- fused forward solves: zc + 10 models (11 ILP chains) ----
        float z[M + 1];
        z[0] = kcv;
        {
            const float* trow = tgt + ((size_t)b * NN + lane) * M;
#pragma unroll
            for (int q = 0; q < M / 2; ++q) {
                const float2 v = *(const float2*)(trow + 2 * q);
                z[2*q + 1] = v.x; z[2*q + 2] = v.y;
            }
        }
        for (int k = 0; k < NN - 1; ++k) {
            float lv = A[k * NN + lane];               // L[lane][k] (junk lane<=k)
            lv = (lane > k) ? -lv : 0.f;
#pragma unroll
            for (int j = 0; j < M + 1; ++j) {
                const float s = rl(z[j], k);
                z[j] = fmaf(lv, s, z[j]);
            }
        }

        // ---- quadratic forms with D^-1 ----
        const float rvv = rvb[lane];
        const float zc  = z[0];
        const float quad = wsum(zc * zc * rvv);
        const float inv_bn = 1.0f / (float)(BATCH * NN);
        unsigned newly = 0;
#pragma unroll
        for (int m = 0; m < M; ++m) {
            if (!(done & (1u << m)) && ls[m] == lls && epsv[m] == lep) {
                const float zm = z[m + 1];
                const float pm = wsum(zc * zm * rvv);
                const float sm = wsum(zm * zm * rvv);
                if (lane == 0) {
                    out[b * M + m] = pm;
                    out[BATCH * M + b * M + m] = 1.0f - quad;
                    atomicAdd(&out[2 * BATCH * M + m], sm * inv_bn);
                }
                newly |= 1u << m;
            }
        }
        done |= newly;
        if (done == all) break;
    }
}

extern "C" void kernel_launch(void* const* d_in, const int* in_sizes, int n_in,
                              void* d_out, int out_size, void* d_ws, size_t ws_size,
                              hipStream_t stream) {
    const float* x   = (const float*)d_in[0];
    const float* lsp = (const float*)d_in[1];
    const float* ep  = (const float*)d_in[2];
    const int*   bi  = (const int*)d_in[3];
    const int*   ni  = (const int*)d_in[4];
    const float* tg  = (const float*)d_in[5];
    float* out = (float*)d_out;

    // sigma_sq region accumulated via atomics; d_out is poisoned each launch
    hipMemsetAsync(out + 2 * BATCH * M, 0, M * sizeof(float), stream);
    muygps_kernel<<<BATCH, 64, 0, stream>>>(x, lsp, ep, bi, ni, tg, out);
}

// Round 10
// 159.827 us; speedup vs baseline: 4.1211x; 2.5673x over previous
//
#include <hip/hip_runtime.h>
#include <math.h>

#define BATCH 2048
#define NN 64
#define FEAT 40
#define M 10
// Row-major 64x64 in LDS; offset-addressed rank-2 updates spill only into
// already-dead (col<k) words; pad to be safe.
#define ASZ (NN * NN + 130)

__device__ __forceinline__ float rl(float v, int l) {
    return __int_as_float(__builtin_amdgcn_readlane(__float_as_int(v), l));
}
__device__ __forceinline__ float wsum(float v) {
#pragma unroll
    for (int o = 32; o >= 1; o >>= 1) v += __shfl_xor(v, o, 64);
    return v;
}

// One wave per batch element (see R9 notes). R10 change: NO same-address
// atomics. R1-R9 all pinned at ~350us wall regardless of compute structure
// because 20480 atomicAdds to one cache line (sigma_sq accumulator)
// serialize at ~30-50cyc each = ~300us; waves wait on vmcnt drain before
// endpgm. sigma contributions now go to d_ws (distinct addresses) and a
// second tiny kernel reduces them.
__global__ __launch_bounds__(64)
void muygps_kernel(
    const float* __restrict__ x,      // (20000, 40)
    const float* __restrict__ ls,     // (10,)
    const float* __restrict__ epsv,   // (10,)
    const int*   __restrict__ bidx,   // (2048,)
    const int*   __restrict__ nidx,   // (2048, 64)
    const float* __restrict__ tgt,    // (2048, 64, 10)
    float* __restrict__ out,          // pred(2048,10) | var(2048,10) | sigma(10)
    float* __restrict__ ws)           // (M, BATCH) raw sigma contributions
{
    __shared__ float A[ASZ];
    __shared__ float rvb[NN];         // 1/D[k]

    const int b    = blockIdx.x;
    const int lane = threadIdx.x;     // one wave

    // ---- lane's neighbor index + row -> 40 statically-indexed VGPRs ----
    const int nv = nidx[b * NN + lane];          // reused for row addressing
    const float* xr0 = x + (size_t)nv * FEAT;
    float xc[FEAT];
#pragma unroll
    for (int q = 0; q < FEAT / 4; ++q) {
        const float4 v = *(const float4*)(xr0 + 4 * q);
        xc[4*q] = v.x; xc[4*q+1] = v.y; xc[4*q+2] = v.z; xc[4*q+3] = v.w;
    }
    float nl = 0.f;
#pragma unroll
    for (int f = 0; f < FEAT; ++f) nl = fmaf(xc[f], xc[f], nl);

    // ---- crosswise distance (batch point via uniform s_loads) ----
    const int bi = __builtin_amdgcn_readfirstlane(bidx[b]);
    const float* xbp = x + (size_t)bi * FEAT;
    float gc = 0.f, nb = 0.f;
#pragma unroll
    for (int f = 0; f < FEAT; ++f) {
        const float bf = xbp[f];
        gc = fmaf(bf, xc[f], gc);
        nb = fmaf(bf, bf, nb);
    }
    float cd2 = (nb + nl) - 2.f * gc;
    cd2 = (cd2 < 0.05f) ? 0.f : cd2;             // dup -> exact 0 (see R9 note)
    const float cdv = sqrtf(cd2);

    unsigned done = 0;
    const unsigned all = (1u << M) - 1u;
    while (true) {
        const int   lead = __ffs(~done) - 1;     // wave-uniform
        const float lls  = ls[lead];
        const float lep  = epsv[lead];
        const float il   = -1.0f / lls;

        // ---- Gram + kernel transform; row i features via uniform s_loads ----
#pragma unroll 2
        for (int i = 0; i < NN; ++i) {
            const int ri = __builtin_amdgcn_readlane(nv, i);   // no global load
            const float* xr = x + (size_t)ri * FEAT;           // -> s_loads
            float g = 0.f;
#pragma unroll
            for (int f = 0; f < FEAT; ++f) g = fmaf(xr[f], xc[f], g);
            const float ni = rl(g, i);           // Gram diag = |x_i|^2
            float d2 = (ni + nl) - 2.f * g;      // dup rows -> exact 0
            d2 = (d2 < 0.05f) ? 0.f : d2;
            float v = __expf(sqrtf(d2) * il);
            if (lane == i) v += lep;
            A[i * NN + lane] = v;
        }
        const float kcv = __expf(cdv * il);

        // ---- rank-2 LDL^T; rows stay symmetric Schur rows ----
        for (int p = 0; p < NN / 2; ++p) {
            const int k  = 2 * p;
            const int kk = k * NN + k;
            const float colv0 = A[kk + lane];              // A[k][k+lane]
            const float d0  = rl(colv0, 0);
            const float r0  = __builtin_amdgcn_rcpf(d0);
            const float cv0 = colv0 * (-r0);
            const float l10 = rl(colv0, 1);
            float colv1 = A[kk + NN + lane];               // A[k+1][k+lane]
            colv1 = fmaf(cv0, l10, colv1);
            const float d1  = rl(colv1, 1);
            const float r1  = __builtin_amdgcn_rcpf(d1);
            const float cv1 = colv1 * (-r1);
            A[kk + lane]      = (lane >= 1) ? colv0 * r0 : 0.f;  // L col k
            A[kk + NN + lane] = (lane >= 2) ? colv1 * r1 : 0.f;  // L col k+1
            rvb[k]     = r0;
            rvb[k + 1] = r1;
#pragma unroll 4
            for (int i = k + 2; i < NN; ++i) {
                const float l0 = rl(colv0, i - k);
                const float l1 = rl(colv1, i - k);
                float t = A[i * NN + k + lane];
                t = fmaf(cv0, l0, t);
                t = fmaf(cv1, l1, t);
                A[i * NN + k + lane] = t;
            }
        }

        // ---- fused forward solves: zc + 10 models (11 ILP chains) ----
        float z[M + 1];
        z[0] = kcv;
        {
            const float* trow = tgt + ((size_t)b * NN + lane) * M;
#pragma unroll
            for (int q = 0; q < M / 2; ++q) {
                const float2 v = *(const float2*)(trow + 2 * q);
                z[2*q + 1] = v.x; z[2*q + 2] = v.y;
            }
        }
        for (int k = 0; k < NN - 1; ++k) {
            float lv = A[k * NN + lane];           // L[lane][k] (junk lane<=k)
            lv = (lane > k) ? -lv : 0.f;
#pragma unroll
            for (int j = 0; j < M + 1; ++j) {
                const float s = rl(z[j], k);
                z[j] = fmaf(lv, s, z[j]);
            }
        }

        // ---- quadratic forms with D^-1; sigma -> ws (NO atomics) ----
        const float rvv = rvb[lane];
        const float zc  = z[0];
        const float quad = wsum(zc * zc * rvv);
        unsigned newly = 0;
#pragma unroll
        for (int m = 0; m < M; ++m) {
            if (!(done & (1u << m)) && ls[m] == lls && epsv[m] == lep) {
                const float zm = z[m + 1];
                const float pm = wsum(zc * zm * rvv);
                const float sm = wsum(zm * zm * rvv);
                if (lane == 0) {
                    out[b * M + m] = pm;
                    out[BATCH * M + b * M + m] = 1.0f - quad;
                    ws[m * BATCH + b] = sm;        // distinct addr, full BW
                }
                newly |= 1u << m;
            }
        }
        done |= newly;
        if (done == all) break;
    }
}

// 10 blocks (one per model) x 256 threads: coalesced sum of ws[m][0..2047].
__global__ __launch_bounds__(256)
void sigma_reduce(const float* __restrict__ ws, float* __restrict__ out) {
    __shared__ float red[4];
    const int m = blockIdx.x;
    const int t = threadIdx.x;
    float a = 0.f;
    for (int i = t; i < BATCH; i += 256) a += ws[m * BATCH + i];
    a = wsum(a);
    if ((t & 63) == 0) red[t >> 6] = a;
    __syncthreads();
    if (t == 0)
        out[2 * BATCH * M + m] =
            (red[0] + red[1] + red[2] + red[3]) * (1.0f / (float)(BATCH * NN));
}

extern "C" void kernel_launch(void* const* d_in, const int* in_sizes, int n_in,
                              void* d_out, int out_size, void* d_ws, size_t ws_size,
                              hipStream_t stream) {
    const float* x   = (const float*)d_in[0];
    const float* lsp = (const float*)d_in[1];
    const float* ep  = (const float*)d_in[2];
    const int*   bi  = (const int*)d_in[3];
    const int*   ni  = (const int*)d_in[4];
    const float* tg  = (const float*)d_in[5];
    float* out = (float*)d_out;
    float* ws  = (float*)d_ws;        // needs M*BATCH*4 = 80 KB

    muygps_kernel<<<BATCH, 64, 0, stream>>>(x, lsp, ep, bi, ni, tg, out, ws);
    sigma_reduce<<<M, 256, 0, stream>>>(ws, out);
}

// Round 11
// 155.954 us; speedup vs baseline: 4.2234x; 1.0248x over previous
//
#include <hip/hip_runtime.h>
#include <math.h>

#define BATCH 2048
#define NN 64
#define FEAT 40
#define M 10
// Row-major 64x64 in LDS; offset-addressed updates/stores reach word
// 63*64+62+63 = 4157; pad covers the spill (lands only in dead col<k words).
#define ASZ (NN * NN + 130)

typedef float v2f __attribute__((ext_vector_type(2)));

// packed f32 fma: acc = a*b + acc (2 lanes of f32 per instruction)
#define PKFMA_SV(acc, s_src, v_src) \
    asm("v_pk_fma_f32 %0, %1, %2, %0" : "+v"(acc) : "s"(s_src), "v"(v_src))
#define PKFMA_VV(acc, a_src, b_src) \
    asm("v_pk_fma_f32 %0, %1, %2, %0" : "+v"(acc) : "v"(a_src), "v"(b_src))

__device__ __forceinline__ float rl(float v, int l) {
    return __int_as_float(__builtin_amdgcn_readlane(__float_as_int(v), l));
}
__device__ __forceinline__ int rli(int v, int l) {
    return __builtin_amdgcn_readlane(v, l);
}
__device__ __forceinline__ float wsum(float v) {
#pragma unroll
    for (int o = 32; o >= 1; o >>= 1) v += __shfl_xor(v, o, 64);
    return v;
}

// One wave per batch element; sigma via d_ws + tiny reducer (R10: removed the
// same-cache-line atomicAdds that floored R1-R9 at ~350us).
// R11: (a) waves_per_eu(2,2): grid limits us to 2 waves/SIMD anyway, so a
// 256-reg budget is FREE -- stops the allocator AGPR-homing xc/z (the
// v_accvgpr copy tax measured as ~2x VALU inflation at VGPR_Count=68).
// (b) v_pk_fma_f32 halves Gram issue. (c) rank-2 LDL^T carries the next two
// pivot rows in registers (shfl_down by 2), deleting the per-step
// ds_read->readlane latency chain and 2 of 4 row-writes.
__global__ __launch_bounds__(64)
__attribute__((amdgpu_waves_per_eu(2, 2)))
void muygps_kernel(
    const float* __restrict__ x,      // (20000, 40)
    const float* __restrict__ ls,     // (10,)
    const float* __restrict__ epsv,   // (10,)
    const int*   __restrict__ bidx,   // (2048,)
    const int*   __restrict__ nidx,   // (2048, 64)
    const float* __restrict__ tgt,    // (2048, 64, 10)
    float* __restrict__ out,          // pred | var | sigma
    float* __restrict__ ws)           // (M, BATCH) sigma contributions
{
    __shared__ float A[ASZ];
    __shared__ float rvb[NN];         // 1/D[k]

    const int b    = blockIdx.x;
    const int lane = threadIdx.x;

    // ---- lane's neighbor row -> 20 v2f pairs (static, SROA-friendly) ----
    const int nv = nidx[b * NN + lane];
    const float* xr0 = x + (size_t)nv * FEAT;
    v2f xc2[FEAT / 2];
#pragma unroll
    for (int q = 0; q < FEAT / 4; ++q) {
        const float4 v = *(const float4*)(xr0 + 4 * q);
        xc2[2 * q]     = v2f{v.x, v.y};
        xc2[2 * q + 1] = v2f{v.z, v.w};
    }
    v2f nl2 = {0.f, 0.f};
#pragma unroll
    for (int q = 0; q < FEAT / 2; ++q) PKFMA_VV(nl2, xc2[q], xc2[q]);
    const float nl = nl2.x + nl2.y;

    // ---- crosswise: batch row via vector loads (same addr all lanes) ----
    const v2f* xbv = (const v2f*)(x + (size_t)bidx[b] * FEAT);
    v2f gc2 = {0.f, 0.f}, nb2 = {0.f, 0.f};
#pragma unroll
    for (int q = 0; q < FEAT / 2; ++q) {
        const v2f xbq = xbv[q];
        PKFMA_VV(gc2, xbq, xc2[q]);   // identical chains -> exact cancel
        PKFMA_VV(nb2, xbq, xbq);      //   when batch point == neighbor
    }
    float cd2 = ((nb2.x + nb2.y) + nl) - 2.f * (gc2.x + gc2.y);
    cd2 = (cd2 < 0.05f) ? 0.f : cd2;  // dup -> exact 0 (legit d2 ~ 80)
    const float cdv = sqrtf(cd2);

    unsigned done = 0;
    const unsigned all = (1u << M) - 1u;
    while (true) {
        const int   lead = __ffs(~done) - 1;     // wave-uniform
        const float lls  = ls[lead];
        const float lep  = epsv[lead];
        const float il   = -1.0f / lls;

        // ---- Gram + kernel transform, 2 rows per iter (pk_fma, s_loads) ----
        for (int i = 0; i < NN; i += 2) {
            const int ri0 = rli(nv, i), ri1 = rli(nv, i + 1);
            const v2f* rp0 = (const v2f*)(x + (size_t)ri0 * FEAT);  // uniform
            const v2f* rp1 = (const v2f*)(x + (size_t)ri1 * FEAT);  //  -> SGPR
            v2f g0 = {0.f, 0.f}, g1 = {0.f, 0.f};
#pragma unroll
            for (int q = 0; q < FEAT / 2; ++q) {
                const v2f r0q = rp0[q], r1q = rp1[q];
                PKFMA_SV(g0, r0q, xc2[q]);
                PKFMA_SV(g1, r1q, xc2[q]);
            }
            const float ga = g0.x + g0.y, gb = g1.x + g1.y;
            float d2a = (rl(ga, i) + nl) - 2.f * ga;       // Gram diag = |x_i|^2
            float d2b = (rl(gb, i + 1) + nl) - 2.f * gb;
            d2a = (d2a < 0.05f) ? 0.f : d2a;
            d2b = (d2b < 0.05f) ? 0.f : d2b;
            float va = __expf(sqrtf(d2a) * il);
            float vb = __expf(sqrtf(d2b) * il);
            if (lane == i)     va += lep;
            if (lane == i + 1) vb += lep;
            A[i * NN + lane]       = va;
            A[(i + 1) * NN + lane] = vb;
        }
        const float kcv = __expf(cdv * il);

        // ---- prefetch targets (hide global latency under factorization) ----
        float z[M + 1];
        z[0] = kcv;
        {
            const float* trow = tgt + ((size_t)b * NN + lane) * M;
#pragma unroll
            for (int q = 0; q < M / 2; ++q) {
                const float2 v = *(const float2*)(trow + 2 * q);
                z[2 * q + 1] = v.x; z[2 * q + 2] = v.y;
            }
        }

        // ---- rank-2 LDL^T with register-carried pivot rows ----
        // pc0 = row k   (cols k+lane, Schur-updated), pc1 = row k+1 (raw-ish)
        float pc0 = A[lane];            // row 0
        float pc1 = A[NN + lane];       // row 1
        for (int p = 0; p < 31; ++p) {
            const int k = 2 * p;
            const float d0  = rl(pc0, 0);
            const float r0  = __builtin_amdgcn_rcpf(d0);
            const float cv0 = pc0 * (-r0);
            pc1 = fmaf(cv0, rl(pc0, 1), pc1);            // rank-1 fix row k+1
            const float d1  = rl(pc1, 1);
            const float r1  = __builtin_amdgcn_rcpf(d1);
            const float cv1 = pc1 * (-r1);
            A[k * NN + k + lane]      = (lane >= 1) ? pc0 * r0 : 0.f;  // L col k
            A[k * NN + NN + k + lane] = (lane >= 2) ? pc1 * r1 : 0.f;  // col k+1
            rvb[k]     = r0;
            rvb[k + 1] = r1;
            // peel rows k+2, k+3 -> registers; they become the next pivots
            float t2 = A[(k + 2) * NN + k + lane];
            float t3 = A[(k + 3) * NN + k + lane];
            t2 = fmaf(cv0, rl(pc0, 2), t2); t2 = fmaf(cv1, rl(pc1, 2), t2);
            t3 = fmaf(cv0, rl(pc0, 3), t3); t3 = fmaf(cv1, rl(pc1, 3), t3);
            const float n0 = __shfl_down(t2, 2, 64);     // shift cols by 2
            const float n1 = __shfl_down(t3, 2, 64);
            for (int i = k + 4; i < NN; ++i) {           // remaining Schur rows
                const float l0 = rl(pc0, i - k);
                const float l1 = rl(pc1, i - k);
                float t = A[i * NN + k + lane];
                t = fmaf(cv0, l0, t);
                t = fmaf(cv1, l1, t);
                A[i * NN + k + lane] = t;
            }
            pc0 = n0; pc1 = n1;
        }
        {   // final step k=62 (no peel, no inner)
            const int k = 62;
            const float d0  = rl(pc0, 0);
            const float r0  = __builtin_amdgcn_rcpf(d0);
            const float cv0 = pc0 * (-r0);
            pc1 = fmaf(cv0, rl(pc0, 1), pc1);
            const float d1  = rl(pc1, 1);
            const float r1  = __builtin_amdgcn_rcpf(d1);
            A[k * NN + k + lane]      = (lane >= 1) ? pc0 * r0 : 0.f;
            A[k * NN + NN + k + lane] = (lane >= 2) ? pc1 * r1 : 0.f;
            rvb[k]     = r0;
            rvb[k + 1] = r1;
        }

        // ---- fused forward solves: zc + 10 models (11 ILP chains) ----
        for (int k = 0; k < NN - 1; ++k) {
            float lv = A[k * NN + lane];          // L[lane][k] (junk lane<=k)
            lv = (lane > k) ? -lv : 0.f;
#pragma unroll
            for (int j = 0; j < M + 1; ++j) {
                const float s = rl(z[j], k);
                z[j] = fmaf(lv, s, z[j]);
            }
        }

        // ---- quadratic forms with D^-1; sigma -> ws (no atomics) ----
        const float rvv = rvb[lane];
        const float zc  = z[0];
        const float quad = wsum(zc * zc * rvv);
        unsigned newly = 0;
#pragma unroll
        for (int m = 0; m < M; ++m) {
            if (!(done & (1u << m)) && ls[m] == lls && epsv[m] == lep) {
                const float zm = z[m + 1];
                const float pm = wsum(zc * zm * rvv);
                const float sm = wsum(zm * zm * rvv);
                if (lane == 0) {
                    out[b * M + m] = pm;
                    out[BATCH * M + b * M + m] = 1.0f - quad;
                    ws[m * BATCH + b] = sm;
                }
                newly |= 1u << m;
            }
        }
        done |= newly;
        if (done == all) break;
    }
}

// 1 block x 640: wave w reduces model w's 2048 contributions (float4 loads).
__global__ __launch_bounds__(640)
void sigma_reduce(const float* __restrict__ ws, float* __restrict__ out) {
    const int w = threadIdx.x >> 6, lane = threadIdx.x & 63;
    const float4* p = (const float4*)(ws + w * BATCH);
    float a = 0.f;
#pragma unroll
    for (int i = 0; i < BATCH / 4 / 64; ++i) {
        const float4 v = p[i * 64 + lane];
        a += (v.x + v.y) + (v.z + v.w);
    }
    a = wsum(a);
    if (lane == 0)
        out[2 * BATCH * M + w] = a * (1.0f / (float)(BATCH * NN));
}

extern "C" void kernel_launch(void* const* d_in, const int* in_sizes, int n_in,
                              void* d_out, int out_size, void* d_ws, size_t ws_size,
                              hipStream_t stream) {
    const float* x   = (const float*)d_in[0];
    const float* lsp = (const float*)d_in[1];
    const float* ep  = (const float*)d_in[2];
    const int*   bi  = (const int*)d_in[3];
    const int*   ni  = (const int*)d_in[4];
    const float* tg  = (const float*)d_in[5];
    float* out = (float*)d_out;
    float* ws  = (float*)d_ws;        // M*BATCH*4 = 80 KB

    muygps_kernel<<<BATCH, 64, 0, stream>>>(x, lsp, ep, bi, ni, tg, out, ws);
    sigma_reduce<<<1, 640, 0, stream>>>(ws, out);
}